// Round 5
// baseline (320.836 us; speedup 1.0000x reference)
//
#include <hip/hip_runtime.h>
#include <math.h>

#define NB 2
#define NR 16384
#define NRAY (NB*NR)   // 32768 rays
#define NS 48
#define NC 32
#define ND 64

// d_ws layout (12 bytes used): [0]=global min bits (uint), [1]=global max bits (uint), [2]=var sum (float)

__global__ void init_ws_kernel(unsigned int* ws) {
    ws[0] = 0x7f7fffffu;   // FLT_MAX bits (depths are positive)
    ws[1] = 0u;
    ((float*)ws)[2] = 0.0f;
}

__device__ __forceinline__ float4 shfl_xor4(float4 v, int m) {
    float4 r;
    r.x = __shfl_xor(v.x, m);
    r.y = __shfl_xor(v.y, m);
    r.z = __shfl_xor(v.z, m);
    r.w = __shfl_xor(v.w, m);
    return r;
}

__global__ __launch_bounds__(256) void march_kernel(
    const float* __restrict__ colors, const float* __restrict__ densities,
    const float* __restrict__ depths, const float* __restrict__ dinos,
    float* __restrict__ out, unsigned int* __restrict__ ws)
{
    const int wid  = threadIdx.x >> 6;
    const int lane = threadIdx.x & 63;
    const int ray  = blockIdx.x * 4 + wid;

    __shared__ float v_sh[4][NS];
    __shared__ float var_sh[4];
    __shared__ float mn_sh[4], mx_sh[4];

    const float* dep = depths    + (size_t)ray * NS;
    const float* den = densities + (size_t)ray * NS;

    float d_i = (lane < NS) ? dep[lane] : 0.f;
    float n_i = (lane < NS) ? den[lane] : 0.f;
    float d_n = __shfl_down(d_i, 1);
    float n_n = __shfl_down(n_i, 1);

    const bool act = (lane < NS - 1);             // 47 intervals
    float delta = d_n - d_i;
    float dm    = 0.5f * (d_i + d_n);             // depths_mid
    float x     = 0.5f * (n_i + n_n) - 1.0f;      // densities_mid - 1
    float sp    = fmaxf(x, 0.f) + log1pf(expf(-fabsf(x)));   // stable softplus
    float alpha = act ? (1.f - expf(-sp * delta)) : 0.f;
    float f     = act ? (1.f - alpha + 1e-10f) : 1.f;

    // per-ray depth min/max (depths sorted along S): endpoints
    float rmn = __shfl(d_i, 0);
    float rmx = __shfl(d_i, NS - 1);
    if (lane == 0) { mn_sh[wid] = rmn; mx_sh[wid] = rmx; }

    // inclusive prefix product (Kogge-Stone) over 64 lanes
    float incl = f;
#pragma unroll
    for (int off = 1; off < 64; off <<= 1) {
        float o = __shfl_up(incl, off);
        if (lane >= off) incl *= o;
    }
    float T = __shfl_up(incl, 1);
    if (lane == 0) T = 1.f;
    float w  = alpha * T;                         // lanes >= 47 have w == 0
    float bg = __shfl(incl, 45);                  // T_46 = prod_{j<=45} f_j

    // butterfly reductions: W = sum w, M = sum w*dm (all lanes get result)
    float W = w, M = w * dm;
#pragma unroll
    for (int off = 32; off > 0; off >>= 1) {
        W += __shfl_xor(W, off);
        M += __shfl_xor(M, off);
    }
    // exact two-pass variance numerator: sum w*(dm - M)^2
    float dv = dm - M;
    float vn = w * dv * dv;
#pragma unroll
    for (int off = 32; off > 0; off >>= 1) vn += __shfl_xor(vn, off);

    // coefficients v_j = 0.5*(w_{j-1} + w_j), j = 0..47 (w_{-1} = w_47 = 0)
    float wprev = __shfl_up(w, 1);
    if (lane == 0) wprev = 0.f;
    float v = 0.5f * (wprev + w);
    if (lane < NS) v_sh[wid][lane] = v;           // same-wave LDS RAW: no barrier needed

    // output chunk bases (return order, flat)
    float* out_rgb = out;
    float* out_dep = out + (size_t)NRAY * NC;
    float* out_w   = out + (size_t)NRAY * (NC + 1);
    float* out_bg  = out + (size_t)NRAY * (NC + 1 + (NS - 1));
    float* out_din = out + (size_t)NRAY * (NC + 2 + (NS - 1));
    float* out_wt  = out + (size_t)NRAY * (NC + 2 + (NS - 1) + ND);

    if (act) out_w[(size_t)ray * (NS - 1) + lane] = w;

    if (lane == 0) {
        float cd = M / W;
        if (cd != cd) cd = INFINITY;              // nan_to_num(nan=inf); clipped later
        out_dep[ray] = cd;
        out_bg[ray]  = bg;
        out_wt[ray]  = W;
        var_sh[wid]  = vn / (W + 1e-6f);
    }

    // composite_rgb: tile t covers samples 8t..8t+7 (8 rows x 8 quads = 1024B/wave-read)
    {
        const float4* cp = (const float4*)(colors + (size_t)ray * (NS * NC));
        const int jr = lane >> 3;
        float4 acc = make_float4(0.f, 0.f, 0.f, 0.f);
#pragma unroll
        for (int t = 0; t < NS / 8; ++t) {
            float vv = v_sh[wid][8 * t + jr];
            float4 c = cp[64 * t + lane];
            acc.x += vv * c.x; acc.y += vv * c.y; acc.z += vv * c.z; acc.w += vv * c.w;
        }
#pragma unroll
        for (int off = 8; off < 64; off <<= 1) {
            float4 o = shfl_xor4(acc, off);
            acc.x += o.x; acc.y += o.y; acc.z += o.z; acc.w += o.w;
        }
        if (lane < 8) {
            float4 r = make_float4(2.f * acc.x - 1.f, 2.f * acc.y - 1.f,
                                   2.f * acc.z - 1.f, 2.f * acc.w - 1.f);
            ((float4*)(out_rgb + (size_t)ray * NC))[lane] = r;
        }
    }

    // composite_dino: tile t covers samples 4t..4t+3 (4 rows x 16 quads = 1024B/wave-read)
    {
        const float4* dp = (const float4*)(dinos + (size_t)ray * (NS * ND));
        const int jr = lane >> 4;
        float4 acc = make_float4(0.f, 0.f, 0.f, 0.f);
#pragma unroll
        for (int t = 0; t < NS / 4; ++t) {
            float vv = v_sh[wid][4 * t + jr];
            float4 c = dp[64 * t + lane];
            acc.x += vv * c.x; acc.y += vv * c.y; acc.z += vv * c.z; acc.w += vv * c.w;
        }
#pragma unroll
        for (int off = 16; off < 64; off <<= 1) {
            float4 o = shfl_xor4(acc, off);
            acc.x += o.x; acc.y += o.y; acc.z += o.z; acc.w += o.w;
        }
        if (lane < 16) {
            float b = 1.f - 2.f * W;   // 2*(acc + 1 - W) - 1 = 2*acc + (1 - 2W)
            float4 r = make_float4(2.f * acc.x + b, 2.f * acc.y + b,
                                   2.f * acc.z + b, 2.f * acc.w + b);
            ((float4*)(out_din + (size_t)ray * ND))[lane] = r;
        }
    }

    __syncthreads();
    if (threadIdx.x == 0) {
        atomicAdd((float*)ws + 2, var_sh[0] + var_sh[1] + var_sh[2] + var_sh[3]);
        float bmn = fminf(fminf(mn_sh[0], mn_sh[1]), fminf(mn_sh[2], mn_sh[3]));
        float bmx = fmaxf(fmaxf(mx_sh[0], mx_sh[1]), fmaxf(mx_sh[2], mx_sh[3]));
        atomicMin(&ws[0], __float_as_uint(bmn));  // uint order == float order for positive floats
        atomicMax(&ws[1], __float_as_uint(bmx));  // fire-and-forget; ordered by kernel boundary
    }
}

__global__ __launch_bounds__(256) void clip_finalize_kernel(
    const unsigned int* __restrict__ ws, float* __restrict__ out)
{
    int i = blockIdx.x * blockDim.x + threadIdx.x;   // 32768 threads
    float gmin = __uint_as_float(ws[0]);
    float gmax = __uint_as_float(ws[1]);
    float* out_dep = out + (size_t)NRAY * NC;
    float cd = out_dep[i];
    out_dep[i] = fminf(fmaxf(cd, gmin), gmax);       // inf -> gmax
    if (i == 0) {
        out[(size_t)NRAY * 146] = ((const float*)ws)[2] * (1.0f / (float)NRAY);
    }
}

extern "C" void kernel_launch(void* const* d_in, const int* in_sizes, int n_in,
                              void* d_out, int out_size, void* d_ws, size_t ws_size,
                              hipStream_t stream) {
    const float* colors    = (const float*)d_in[0];
    const float* densities = (const float*)d_in[1];
    const float* depths    = (const float*)d_in[2];
    const float* dinos     = (const float*)d_in[3];
    float* out = (float*)d_out;
    unsigned int* ws = (unsigned int*)d_ws;

    hipLaunchKernelGGL(init_ws_kernel, dim3(1), dim3(1), 0, stream, ws);
    hipLaunchKernelGGL(march_kernel, dim3(NRAY / 4), dim3(256), 0, stream,
                       colors, densities, depths, dinos, out, ws);
    hipLaunchKernelGGL(clip_finalize_kernel, dim3(NRAY / 256), dim3(256), 0, stream,
                       (const unsigned int*)ws, out);
}

// Round 6
// 164.248 us; speedup vs baseline: 1.9534x; 1.9534x over previous
//
#include <hip/hip_runtime.h>
#include <math.h>

#define NB 2
#define NR 16384
#define NRAY (NB*NR)   // 32768 rays
#define NS 48
#define NC 32
#define ND 64

typedef float fvec4 __attribute__((ext_vector_type(4)));

// d_ws layout (12 bytes used): [0]=global min bits (uint), [1]=global max bits (uint), [2]=var sum (float)

__global__ void init_ws_kernel(unsigned int* ws) {
    ws[0] = 0x7f7fffffu;   // FLT_MAX bits (depths are positive)
    ws[1] = 0u;
    ((float*)ws)[2] = 0.0f;
}

__global__ void minmax_kernel(const float* __restrict__ depths, unsigned int* __restrict__ ws) {
    int ray = blockIdx.x * blockDim.x + threadIdx.x;   // 32768 threads
    // depths are sorted along S, so per-ray min/max are the endpoints
    float mn = depths[(size_t)ray * NS];
    float mx = depths[(size_t)ray * NS + (NS - 1)];
#pragma unroll
    for (int off = 32; off > 0; off >>= 1) {
        mn = fminf(mn, __shfl_xor(mn, off));
        mx = fmaxf(mx, __shfl_xor(mx, off));
    }
    if ((threadIdx.x & 63) == 0) {
        atomicMin(&ws[0], __float_as_uint(mn));   // uint order == float order for positive floats
        atomicMax(&ws[1], __float_as_uint(mx));
    }
}

__device__ __forceinline__ fvec4 shfl_xor4v(fvec4 v, int m) {
    fvec4 r;
    r[0] = __shfl_xor(v[0], m);
    r[1] = __shfl_xor(v[1], m);
    r[2] = __shfl_xor(v[2], m);
    r[3] = __shfl_xor(v[3], m);
    return r;
}

__global__ __launch_bounds__(256) void march_kernel(
    const float* __restrict__ colors, const float* __restrict__ densities,
    const float* __restrict__ depths, const float* __restrict__ dinos,
    float* __restrict__ out, const unsigned int* __restrict__ ws_mm,
    float* __restrict__ ws_var)
{
    const int wid  = threadIdx.x >> 6;
    const int lane = threadIdx.x & 63;
    const int ray  = blockIdx.x * 4 + wid;

    __shared__ float v_sh[4][NS];
    __shared__ float var_sh[4];

    const float* dep = depths    + (size_t)ray * NS;
    const float* den = densities + (size_t)ray * NS;

    float d_i = (lane < NS) ? dep[lane] : 0.f;
    float n_i = (lane < NS) ? den[lane] : 0.f;
    float d_n = __shfl_down(d_i, 1);
    float n_n = __shfl_down(n_i, 1);

    const bool act = (lane < NS - 1);             // 47 intervals
    float delta = d_n - d_i;
    float dm    = 0.5f * (d_i + d_n);             // depths_mid
    float x     = 0.5f * (n_i + n_n) - 1.0f;      // densities_mid - 1
    float sp    = fmaxf(x, 0.f) + log1pf(expf(-fabsf(x)));   // stable softplus
    float alpha = act ? (1.f - expf(-sp * delta)) : 0.f;
    float f     = act ? (1.f - alpha + 1e-10f) : 1.f;

    // inclusive prefix product (Kogge-Stone) over 64 lanes
    float incl = f;
#pragma unroll
    for (int off = 1; off < 64; off <<= 1) {
        float o = __shfl_up(incl, off);
        if (lane >= off) incl *= o;
    }
    float T = __shfl_up(incl, 1);
    if (lane == 0) T = 1.f;
    float w  = alpha * T;                         // lanes >= 47 have w == 0
    float bg = __shfl(incl, 45);                  // T_46 = prod_{j<=45} f_j

    // butterfly reductions: W = sum w, M = sum w*dm (all lanes get result)
    float W = w, M = w * dm;
#pragma unroll
    for (int off = 32; off > 0; off >>= 1) {
        W += __shfl_xor(W, off);
        M += __shfl_xor(M, off);
    }
    // exact two-pass variance numerator: sum w*(dm - M)^2
    float dv = dm - M;
    float vn = w * dv * dv;
#pragma unroll
    for (int off = 32; off > 0; off >>= 1) vn += __shfl_xor(vn, off);

    // coefficients v_j = 0.5*(w_{j-1} + w_j), j = 0..47 (w_{-1} = w_47 = 0)
    float wprev = __shfl_up(w, 1);
    if (lane == 0) wprev = 0.f;
    float v = 0.5f * (wprev + w);
    if (lane < NS) v_sh[wid][lane] = v;           // same-wave LDS RAW: no barrier needed

    // output chunk bases (return order, flat)
    float* out_rgb = out;
    float* out_dep = out + (size_t)NRAY * NC;
    float* out_w   = out + (size_t)NRAY * (NC + 1);
    float* out_bg  = out + (size_t)NRAY * (NC + 1 + (NS - 1));
    float* out_din = out + (size_t)NRAY * (NC + 2 + (NS - 1));
    float* out_wt  = out + (size_t)NRAY * (NC + 2 + (NS - 1) + ND);

    if (act) out_w[(size_t)ray * (NS - 1) + lane] = w;

    if (lane == 0) {
        float cd = M / W;
        if (cd != cd) cd = INFINITY;              // nan_to_num(nan=inf)
        float gmin = __uint_as_float(ws_mm[0]);
        float gmax = __uint_as_float(ws_mm[1]);
        cd = fminf(fmaxf(cd, gmin), gmax);        // clip (inf -> gmax)
        out_dep[ray] = cd;
        out_bg[ray]  = bg;
        out_wt[ray]  = W;
        var_sh[wid]  = vn / (W + 1e-6f);
    }

    // composite_rgb: tile t covers samples 8t..8t+7 (8 rows x 8 quads = 1024B/wave-read)
    // nontemporal: colors have zero reuse -> bypass L2/L3, stream from HBM
    {
        const fvec4* cp = (const fvec4*)(colors + (size_t)ray * (NS * NC));
        const int jr = lane >> 3;
        fvec4 acc = {0.f, 0.f, 0.f, 0.f};
#pragma unroll
        for (int t = 0; t < NS / 8; ++t) {
            float vv = v_sh[wid][8 * t + jr];
            fvec4 c = __builtin_nontemporal_load(cp + 64 * t + lane);
            acc += vv * c;
        }
#pragma unroll
        for (int off = 8; off < 64; off <<= 1) {
            acc += shfl_xor4v(acc, off);
        }
        if (lane < 8) {
            float4 r = make_float4(2.f * acc[0] - 1.f, 2.f * acc[1] - 1.f,
                                   2.f * acc[2] - 1.f, 2.f * acc[3] - 1.f);
            ((float4*)(out_rgb + (size_t)ray * NC))[lane] = r;
        }
    }

    // composite_dino: tile t covers samples 4t..4t+3 (4 rows x 16 quads = 1024B/wave-read)
    {
        const fvec4* dp = (const fvec4*)(dinos + (size_t)ray * (NS * ND));
        const int jr = lane >> 4;
        fvec4 acc = {0.f, 0.f, 0.f, 0.f};
#pragma unroll
        for (int t = 0; t < NS / 4; ++t) {
            float vv = v_sh[wid][4 * t + jr];
            fvec4 c = __builtin_nontemporal_load(dp + 64 * t + lane);
            acc += vv * c;
        }
#pragma unroll
        for (int off = 16; off < 64; off <<= 1) {
            acc += shfl_xor4v(acc, off);
        }
        if (lane < 16) {
            float b = 1.f - 2.f * W;   // 2*(acc + 1 - W) - 1 = 2*acc + (1 - 2W)
            float4 r = make_float4(2.f * acc[0] + b, 2.f * acc[1] + b,
                                   2.f * acc[2] + b, 2.f * acc[3] + b);
            ((float4*)(out_din + (size_t)ray * ND))[lane] = r;
        }
    }

    __syncthreads();
    if (threadIdx.x == 0) {
        atomicAdd(ws_var, var_sh[0] + var_sh[1] + var_sh[2] + var_sh[3]);
    }
}

__global__ void finalize_kernel(const float* __restrict__ ws, float* __restrict__ out) {
    out[(size_t)NRAY * 146] = ws[2] * (1.0f / (float)NRAY);   // mean over B*R rays
}

extern "C" void kernel_launch(void* const* d_in, const int* in_sizes, int n_in,
                              void* d_out, int out_size, void* d_ws, size_t ws_size,
                              hipStream_t stream) {
    const float* colors    = (const float*)d_in[0];
    const float* densities = (const float*)d_in[1];
    const float* depths    = (const float*)d_in[2];
    const float* dinos     = (const float*)d_in[3];
    float* out = (float*)d_out;
    unsigned int* ws = (unsigned int*)d_ws;

    hipLaunchKernelGGL(init_ws_kernel, dim3(1), dim3(1), 0, stream, ws);
    hipLaunchKernelGGL(minmax_kernel, dim3(NRAY / 256), dim3(256), 0, stream, depths, ws);
    hipLaunchKernelGGL(march_kernel, dim3(NRAY / 4), dim3(256), 0, stream,
                       colors, densities, depths, dinos, out, ws, (float*)ws + 2);
    hipLaunchKernelGGL(finalize_kernel, dim3(1), dim3(1), 0, stream, (const float*)ws, out);
}

// Round 7
// 151.490 us; speedup vs baseline: 2.1179x; 1.0842x over previous
//
#include <hip/hip_runtime.h>
#include <math.h>

#define NB 2
#define NR 16384
#define NRAY (NB*NR)   // 32768 rays
#define NS 48
#define NC 32
#define ND 64
#define NBLK (NRAY/4)  // 8192 march blocks

// d_ws layout: [0]=global min bits (uint), [1]=global max bits (uint), [2..3] pad,
//              floats [4 .. 4+NBLK) = per-block var partials

__global__ void init_ws_kernel(unsigned int* ws) {
    ws[0] = 0x7f7fffffu;   // FLT_MAX bits (depths are positive)
    ws[1] = 0u;
}

__global__ void minmax_kernel(const float* __restrict__ depths, unsigned int* __restrict__ ws) {
    int ray = blockIdx.x * blockDim.x + threadIdx.x;   // 32768 threads
    // depths are sorted along S, so per-ray min/max are the endpoints
    float mn = depths[(size_t)ray * NS];
    float mx = depths[(size_t)ray * NS + (NS - 1)];
#pragma unroll
    for (int off = 32; off > 0; off >>= 1) {
        mn = fminf(mn, __shfl_xor(mn, off));
        mx = fmaxf(mx, __shfl_xor(mx, off));
    }
    if ((threadIdx.x & 63) == 0) {
        atomicMin(&ws[0], __float_as_uint(mn));   // uint order == float order for positive floats
        atomicMax(&ws[1], __float_as_uint(mx));   // only 512 of these, spread out
    }
}

__device__ __forceinline__ float4 shfl_xor4(float4 v, int m) {
    float4 r;
    r.x = __shfl_xor(v.x, m);
    r.y = __shfl_xor(v.y, m);
    r.z = __shfl_xor(v.z, m);
    r.w = __shfl_xor(v.w, m);
    return r;
}

__global__ __launch_bounds__(256) void march_kernel(
    const float* __restrict__ colors, const float* __restrict__ densities,
    const float* __restrict__ depths, const float* __restrict__ dinos,
    float* __restrict__ out, const unsigned int* __restrict__ ws_mm,
    float* __restrict__ vb)
{
    const int wid  = threadIdx.x >> 6;
    const int lane = threadIdx.x & 63;
    const int ray  = blockIdx.x * 4 + wid;

    __shared__ float v_sh[4][NS];
    __shared__ float var_sh[4];

    const float* dep = depths    + (size_t)ray * NS;
    const float* den = densities + (size_t)ray * NS;

    float d_i = (lane < NS) ? dep[lane] : 0.f;
    float n_i = (lane < NS) ? den[lane] : 0.f;
    float d_n = __shfl_down(d_i, 1);
    float n_n = __shfl_down(n_i, 1);

    const bool act = (lane < NS - 1);             // 47 intervals
    float delta = d_n - d_i;
    float dm    = 0.5f * (d_i + d_n);             // depths_mid
    float x     = 0.5f * (n_i + n_n) - 1.0f;      // densities_mid - 1
    float sp    = fmaxf(x, 0.f) + log1pf(expf(-fabsf(x)));   // stable softplus
    float alpha = act ? (1.f - expf(-sp * delta)) : 0.f;
    float f     = act ? (1.f - alpha + 1e-10f) : 1.f;

    // inclusive prefix product (Kogge-Stone) over 64 lanes
    float incl = f;
#pragma unroll
    for (int off = 1; off < 64; off <<= 1) {
        float o = __shfl_up(incl, off);
        if (lane >= off) incl *= o;
    }
    float T = __shfl_up(incl, 1);
    if (lane == 0) T = 1.f;
    float w  = alpha * T;                         // lanes >= 47 have w == 0
    float bg = __shfl(incl, 45);                  // T_46 = prod_{j<=45} f_j

    // butterfly reductions: W = sum w, M = sum w*dm (all lanes get result)
    float W = w, M = w * dm;
#pragma unroll
    for (int off = 32; off > 0; off >>= 1) {
        W += __shfl_xor(W, off);
        M += __shfl_xor(M, off);
    }
    // exact two-pass variance numerator: sum w*(dm - M)^2
    float dv = dm - M;
    float vn = w * dv * dv;
#pragma unroll
    for (int off = 32; off > 0; off >>= 1) vn += __shfl_xor(vn, off);

    // coefficients v_j = 0.5*(w_{j-1} + w_j), j = 0..47 (w_{-1} = w_47 = 0)
    float wprev = __shfl_up(w, 1);
    if (lane == 0) wprev = 0.f;
    float v = 0.5f * (wprev + w);
    if (lane < NS) v_sh[wid][lane] = v;           // same-wave LDS RAW: no barrier needed

    // output chunk bases (return order, flat)
    float* out_rgb = out;
    float* out_dep = out + (size_t)NRAY * NC;
    float* out_w   = out + (size_t)NRAY * (NC + 1);
    float* out_bg  = out + (size_t)NRAY * (NC + 1 + (NS - 1));
    float* out_din = out + (size_t)NRAY * (NC + 2 + (NS - 1));
    float* out_wt  = out + (size_t)NRAY * (NC + 2 + (NS - 1) + ND);

    if (act) out_w[(size_t)ray * (NS - 1) + lane] = w;

    if (lane == 0) {
        float cd = M / W;
        if (cd != cd) cd = INFINITY;              // nan_to_num(nan=inf)
        float gmin = __uint_as_float(ws_mm[0]);
        float gmax = __uint_as_float(ws_mm[1]);
        cd = fminf(fmaxf(cd, gmin), gmax);        // clip (inf -> gmax)
        out_dep[ray] = cd;
        out_bg[ray]  = bg;
        out_wt[ray]  = W;
        var_sh[wid]  = vn / (W + 1e-6f);
    }

    // composite_rgb: tile t covers samples 8t..8t+7 (8 rows x 8 quads = 1024B/wave-read)
    {
        const float4* cp = (const float4*)(colors + (size_t)ray * (NS * NC));
        const int jr = lane >> 3;
        float4 acc = make_float4(0.f, 0.f, 0.f, 0.f);
#pragma unroll
        for (int t = 0; t < NS / 8; ++t) {
            float vv = v_sh[wid][8 * t + jr];
            float4 c = cp[64 * t + lane];
            acc.x += vv * c.x; acc.y += vv * c.y; acc.z += vv * c.z; acc.w += vv * c.w;
        }
#pragma unroll
        for (int off = 8; off < 64; off <<= 1) {
            float4 o = shfl_xor4(acc, off);
            acc.x += o.x; acc.y += o.y; acc.z += o.z; acc.w += o.w;
        }
        if (lane < 8) {
            float4 r = make_float4(2.f * acc.x - 1.f, 2.f * acc.y - 1.f,
                                   2.f * acc.z - 1.f, 2.f * acc.w - 1.f);
            ((float4*)(out_rgb + (size_t)ray * NC))[lane] = r;
        }
    }

    // composite_dino: tile t covers samples 4t..4t+3 (4 rows x 16 quads = 1024B/wave-read)
    {
        const float4* dp = (const float4*)(dinos + (size_t)ray * (NS * ND));
        const int jr = lane >> 4;
        float4 acc = make_float4(0.f, 0.f, 0.f, 0.f);
#pragma unroll
        for (int t = 0; t < NS / 4; ++t) {
            float vv = v_sh[wid][4 * t + jr];
            float4 c = dp[64 * t + lane];
            acc.x += vv * c.x; acc.y += vv * c.y; acc.z += vv * c.z; acc.w += vv * c.w;
        }
#pragma unroll
        for (int off = 16; off < 64; off <<= 1) {
            float4 o = shfl_xor4(acc, off);
            acc.x += o.x; acc.y += o.y; acc.z += o.z; acc.w += o.w;
        }
        if (lane < 16) {
            float b = 1.f - 2.f * W;   // 2*(acc + 1 - W) - 1 = 2*acc + (1 - 2W)
            float4 r = make_float4(2.f * acc.x + b, 2.f * acc.y + b,
                                   2.f * acc.z + b, 2.f * acc.w + b);
            ((float4*)(out_din + (size_t)ray * ND))[lane] = r;
        }
    }

    __syncthreads();
    if (threadIdx.x == 0) {
        // NO device atomic: plain per-block store, reduced by finalize_kernel
        vb[blockIdx.x] = var_sh[0] + var_sh[1] + var_sh[2] + var_sh[3];
    }
}

__global__ __launch_bounds__(256) void finalize_kernel(
    const float* __restrict__ vb, float* __restrict__ out)
{
    float s = 0.f;
    for (int i = threadIdx.x; i < NBLK; i += 256) s += vb[i];
#pragma unroll
    for (int off = 32; off > 0; off >>= 1) s += __shfl_xor(s, off);
    __shared__ float sh[4];
    if ((threadIdx.x & 63) == 0) sh[threadIdx.x >> 6] = s;
    __syncthreads();
    if (threadIdx.x == 0)
        out[(size_t)NRAY * 146] = (sh[0] + sh[1] + sh[2] + sh[3]) * (1.0f / (float)NRAY);
}

extern "C" void kernel_launch(void* const* d_in, const int* in_sizes, int n_in,
                              void* d_out, int out_size, void* d_ws, size_t ws_size,
                              hipStream_t stream) {
    const float* colors    = (const float*)d_in[0];
    const float* densities = (const float*)d_in[1];
    const float* depths    = (const float*)d_in[2];
    const float* dinos     = (const float*)d_in[3];
    float* out = (float*)d_out;
    unsigned int* ws = (unsigned int*)d_ws;
    float* vb = (float*)ws + 4;   // per-block var partials

    hipLaunchKernelGGL(init_ws_kernel, dim3(1), dim3(1), 0, stream, ws);
    hipLaunchKernelGGL(minmax_kernel, dim3(NRAY / 256), dim3(256), 0, stream, depths, ws);
    hipLaunchKernelGGL(march_kernel, dim3(NBLK), dim3(256), 0, stream,
                       colors, densities, depths, dinos, out, ws, vb);
    hipLaunchKernelGGL(finalize_kernel, dim3(1), dim3(256), 0, stream, (const float*)vb, out);
}